// Round 2
// baseline (729.819 us; speedup 1.0000x reference)
//
#include <hip/hip_runtime.h>
#include <hip/hip_bf16.h>

#define N_NODES 40000
#define N_EDGES 640000
#define D 128
#define NLAYERS 3
#define BN_EPS 1e-5f

using short8 = __attribute__((ext_vector_type(8))) short;
using f32x4  = __attribute__((ext_vector_type(4))) float;

static __device__ __forceinline__ unsigned short f2bf(float f) {
    unsigned u = __float_as_uint(f);
    unsigned r = (u + 0x7fffu + ((u >> 16) & 1u)) >> 16;   // RNE
    return (unsigned short)r;
}
static __device__ __forceinline__ float bf2f(unsigned short h) {
    return __uint_as_float((unsigned)h << 16);
}

// ---------------- CSR build (dst is invariant across layers) ----------------
__global__ void k_hist(const int* __restrict__ dst, int* __restrict__ cnt) {
    int i = blockIdx.x * blockDim.x + threadIdx.x;
    if (i < N_EDGES) atomicAdd(&cnt[dst[i]], 1);
}

__global__ void k_scan(const int* __restrict__ cnt, int* __restrict__ row_ptr,
                       int* __restrict__ row_run) {
    __shared__ int part[256];
    __shared__ int base[256];
    const int CH = (N_NODES + 255) / 256;   // 157
    int t = threadIdx.x;
    int lo = t * CH, hi = min(lo + CH, N_NODES);
    int s = 0;
    for (int i = lo; i < hi; ++i) s += cnt[i];
    part[t] = s;
    __syncthreads();
    if (t == 0) {
        int r = 0;
        for (int i = 0; i < 256; ++i) { base[i] = r; r += part[i]; }
    }
    __syncthreads();
    int r = base[t];
    for (int i = lo; i < hi; ++i) { row_ptr[i] = r; row_run[i] = r; r += cnt[i]; }
    if (t == 255) row_ptr[N_NODES] = r;   // == N_EDGES
}

__global__ void k_scatter(const int* __restrict__ src, const int* __restrict__ dst,
                          const float* __restrict__ ew, int* __restrict__ row_run,
                          int2* __restrict__ edata) {
    int i = blockIdx.x * blockDim.x + threadIdx.x;
    if (i < N_EDGES) {
        int d = dst[i];
        int pos = atomicAdd(&row_run[d], 1);
        edata[pos] = make_int2(src[i], __float_as_int(ew[i]));
    }
}

// ---------------- weight transpose + bf16 hi/lo convert (once) ----------------
__global__ void k_wconv(const float* __restrict__ W1, const float* __restrict__ W2,
                        unsigned short* __restrict__ W1th, unsigned short* __restrict__ W1tl,
                        unsigned short* __restrict__ W2th, unsigned short* __restrict__ W2tl) {
    int i = blockIdx.x * blockDim.x + threadIdx.x;
    if (i >= NLAYERS * D * D) return;
    int l = i / (D * D);
    int r = i % (D * D);
    int k = r / D, c = r % D;
    int oidx = l * D * D + c * D + k;
    float w1 = W1[l * D * D + k * D + c];
    unsigned short h1 = f2bf(w1);
    W1th[oidx] = h1;
    W1tl[oidx] = f2bf(w1 - bf2f(h1));
    float w2 = W2[l * D * D + k * D + c];
    unsigned short h2 = f2bf(w2);
    W2th[oidx] = h2;
    W2tl[oidx] = f2bf(w2 - bf2f(h2));
}

// -------- aggregation: x = (1+eps)*h + sum_e ew*h[src], h = relu(bn(prev)) fused --------
// outputs x as hi/lo bf16 planes (packed 2 per uint)
template <int USE_BN>
__global__ __launch_bounds__(256) void k_agg(
        const float* __restrict__ hin, const float* __restrict__ stats,
        const float* __restrict__ gamma, const float* __restrict__ beta,
        const int* __restrict__ row_ptr, const int2* __restrict__ edata,
        const float* __restrict__ eps_list, int layer,
        unsigned int* __restrict__ xh, unsigned int* __restrict__ xl) {
    __shared__ float sc[D], sh[D];
    int tid = threadIdx.x;
    if (USE_BN) {
        if (tid < D) {
            float s = stats[tid], q = stats[D + tid];
            float mean = s * (1.0f / N_NODES);
            float var  = q * (1.0f / N_NODES) - mean * mean;
            float inv  = rsqrtf(var + BN_EPS);
            float scale = gamma[tid] * inv;
            sc[tid] = scale;
            sh[tid] = beta[tid] - mean * scale;
        }
        __syncthreads();
    }
    int wv = tid >> 6, lane = tid & 63;
    int node = blockIdx.x * 4 + wv;   // grid = N_NODES/4 exactly

    float sc0 = 1.f, sh0 = 0.f, sc1 = 1.f, sh1 = 0.f;
    if (USE_BN) { sc0 = sc[2 * lane]; sh0 = sh[2 * lane]; sc1 = sc[2 * lane + 1]; sh1 = sh[2 * lane + 1]; }

    const float2* h2 = (const float2*)hin;
    float2 acc = make_float2(0.f, 0.f);
    int e = row_ptr[node], end = row_ptr[node + 1];
    for (; e + 1 < end; e += 2) {
        int2 e0 = edata[e], e1 = edata[e + 1];
        float2 v0 = h2[e0.x * 64 + lane];
        float2 v1 = h2[e1.x * 64 + lane];
        float w0 = __int_as_float(e0.y), w1 = __int_as_float(e1.y);
        if (USE_BN) {
            v0.x = fmaxf(0.f, sc0 * v0.x + sh0); v0.y = fmaxf(0.f, sc1 * v0.y + sh1);
            v1.x = fmaxf(0.f, sc0 * v1.x + sh0); v1.y = fmaxf(0.f, sc1 * v1.y + sh1);
        }
        acc.x = fmaf(w0, v0.x, acc.x); acc.y = fmaf(w0, v0.y, acc.y);
        acc.x = fmaf(w1, v1.x, acc.x); acc.y = fmaf(w1, v1.y, acc.y);
    }
    if (e < end) {
        int2 e0 = edata[e];
        float2 v0 = h2[e0.x * 64 + lane];
        float w0 = __int_as_float(e0.y);
        if (USE_BN) {
            v0.x = fmaxf(0.f, sc0 * v0.x + sh0); v0.y = fmaxf(0.f, sc1 * v0.y + sh1);
        }
        acc.x = fmaf(w0, v0.x, acc.x); acc.y = fmaf(w0, v0.y, acc.y);
    }
    float2 hv = h2[node * 64 + lane];
    if (USE_BN) {
        hv.x = fmaxf(0.f, sc0 * hv.x + sh0); hv.y = fmaxf(0.f, sc1 * hv.y + sh1);
    }
    float ep = 1.0f + eps_list[layer];
    float x0 = fmaf(ep, hv.x, acc.x);
    float x1 = fmaf(ep, hv.y, acc.y);
    unsigned short h0 = f2bf(x0), h1 = f2bf(x1);
    unsigned short l0 = f2bf(x0 - bf2f(h0)), l1 = f2bf(x1 - bf2f(h1));
    xh[node * 64 + lane] = (unsigned)h0 | ((unsigned)h1 << 16);
    xl[node * 64 + lane] = (unsigned)l0 | ((unsigned)l1 << 16);
}

// ---------------- GEMM1: y = x @ W1t + b1  (split-bf16, ~fp24 precision) ----------------
__global__ __launch_bounds__(256) void k_gemm1(
        const unsigned int* __restrict__ xh, const unsigned int* __restrict__ xl,
        const unsigned short* __restrict__ Wth, const unsigned short* __restrict__ Wtl,
        const float* __restrict__ b1, float* __restrict__ y) {
    int tid = threadIdx.x, wv = tid >> 6, lane = tid & 63;
    int lr = lane & 15, lk = lane >> 4;
    int rowBase = blockIdx.x * 64 + wv * 16;
    f32x4 acc[8];
    #pragma unroll
    for (int nt = 0; nt < 8; ++nt) acc[nt] = (f32x4){0.f, 0.f, 0.f, 0.f};

    const short8* xrowh = (const short8*)((const unsigned short*)xh + (rowBase + lr) * D);
    const short8* xrowl = (const short8*)((const unsigned short*)xl + (rowBase + lr) * D);
    #pragma unroll
    for (int kk = 0; kk < 4; ++kk) {
        short8 ah = xrowh[kk * 4 + lk];
        short8 al = xrowl[kk * 4 + lk];
        #pragma unroll
        for (int nt = 0; nt < 8; ++nt) {
            const short8* wrowh = (const short8*)(Wth + (nt * 16 + lr) * D);
            const short8* wrowl = (const short8*)(Wtl + (nt * 16 + lr) * D);
            short8 bh = wrowh[kk * 4 + lk];
            short8 bl = wrowl[kk * 4 + lk];
            acc[nt] = __builtin_amdgcn_mfma_f32_16x16x32_bf16(ah, bh, acc[nt], 0, 0, 0);
            acc[nt] = __builtin_amdgcn_mfma_f32_16x16x32_bf16(ah, bl, acc[nt], 0, 0, 0);
            acc[nt] = __builtin_amdgcn_mfma_f32_16x16x32_bf16(al, bh, acc[nt], 0, 0, 0);
        }
    }
    #pragma unroll
    for (int nt = 0; nt < 8; ++nt) {
        int col = nt * 16 + lr;
        float bias = b1[col];
        #pragma unroll
        for (int j = 0; j < 4; ++j) {
            int row = rowBase + lk * 4 + j;
            y[row * D + col] = acc[nt][j] + bias;
        }
    }
}

// ------------- GEMM2: t2 = relu( relu(bn1(y)) @ W2t + b2 )  (split-bf16) -------------
__global__ __launch_bounds__(256) void k_gemm2(
        const float* __restrict__ y, const float* __restrict__ stats1,
        const float* __restrict__ g1, const float* __restrict__ bt1,
        const unsigned short* __restrict__ Wth, const unsigned short* __restrict__ Wtl,
        const float* __restrict__ b2, float* __restrict__ t2) {
    __shared__ float sc[D], sh[D];
    int tid = threadIdx.x;
    if (tid < D) {
        float s = stats1[tid], q = stats1[D + tid];
        float mean = s * (1.0f / N_NODES);
        float var  = q * (1.0f / N_NODES) - mean * mean;
        float inv  = rsqrtf(var + BN_EPS);
        float scale = g1[tid] * inv;
        sc[tid] = scale;
        sh[tid] = bt1[tid] - mean * scale;
    }
    __syncthreads();

    int wv = tid >> 6, lane = tid & 63;
    int lr = lane & 15, lk = lane >> 4;
    int rowBase = blockIdx.x * 64 + wv * 16;
    f32x4 acc[8];
    #pragma unroll
    for (int nt = 0; nt < 8; ++nt) acc[nt] = (f32x4){0.f, 0.f, 0.f, 0.f};

    const float* yrow = y + (rowBase + lr) * D;
    #pragma unroll
    for (int kk = 0; kk < 4; ++kk) {
        int k0 = kk * 32 + lk * 8;
        float vv[8];
        *(float4*)&vv[0] = *(const float4*)(yrow + k0);
        *(float4*)&vv[4] = *(const float4*)(yrow + k0 + 4);
        short8 ah, al;
        #pragma unroll
        for (int i = 0; i < 8; ++i) {
            float t = fmaxf(0.f, sc[k0 + i] * vv[i] + sh[k0 + i]);
            unsigned short hi = f2bf(t);
            ah[i] = (short)hi;
            al[i] = (short)f2bf(t - bf2f(hi));
        }
        #pragma unroll
        for (int nt = 0; nt < 8; ++nt) {
            const short8* wrowh = (const short8*)(Wth + (nt * 16 + lr) * D);
            const short8* wrowl = (const short8*)(Wtl + (nt * 16 + lr) * D);
            short8 bh = wrowh[kk * 4 + lk];
            short8 bl = wrowl[kk * 4 + lk];
            acc[nt] = __builtin_amdgcn_mfma_f32_16x16x32_bf16(ah, bh, acc[nt], 0, 0, 0);
            acc[nt] = __builtin_amdgcn_mfma_f32_16x16x32_bf16(ah, bl, acc[nt], 0, 0, 0);
            acc[nt] = __builtin_amdgcn_mfma_f32_16x16x32_bf16(al, bh, acc[nt], 0, 0, 0);
        }
    }
    #pragma unroll
    for (int nt = 0; nt < 8; ++nt) {
        int col = nt * 16 + lr;
        float bias = b2[col];
        #pragma unroll
        for (int j = 0; j < 4; ++j) {
            int row = rowBase + lk * 4 + j;
            t2[row * D + col] = fmaxf(0.f, acc[nt][j] + bias);
        }
    }
}

// ---------------- column stats: stats[c] += sum, stats[D+c] += sumsq ----------------
__global__ __launch_bounds__(256) void k_stats(const float* __restrict__ m,
                                               float* __restrict__ stats) {
    __shared__ float bs[256], bq[256];
    int tid = threadIdx.x;
    int col = tid & (D - 1), half = tid >> 7;
    int r0 = (int)blockIdx.x * 128 + half;
    int rend = min((int)(blockIdx.x + 1) * 128, N_NODES);
    float s = 0.f, q = 0.f;
    for (int r = r0; r < rend; r += 2) {
        float v = m[r * D + col];
        s += v; q += v * v;
    }
    bs[tid] = s; bq[tid] = q;
    __syncthreads();
    if (tid < 128) {
        s = bs[tid] + bs[tid + 128];
        q = bq[tid] + bq[tid + 128];
        atomicAdd(&stats[col], s);
        atomicAdd(&stats[D + col], q);
    }
}

// ---------------- final output: out = relu(bn2(t2)) ----------------
__global__ __launch_bounds__(256) void k_bnout(
        const float* __restrict__ t2, const float* __restrict__ stats,
        const float* __restrict__ gamma, const float* __restrict__ beta,
        float* __restrict__ out) {
    __shared__ float sc[D], sh[D];
    int tid = threadIdx.x;
    if (tid < D) {
        float s = stats[tid], q = stats[D + tid];
        float mean = s * (1.0f / N_NODES);
        float var  = q * (1.0f / N_NODES) - mean * mean;
        float inv  = rsqrtf(var + BN_EPS);
        float scale = gamma[tid] * inv;
        sc[tid] = scale;
        sh[tid] = beta[tid] - mean * scale;
    }
    __syncthreads();
    int i = blockIdx.x * blockDim.x + tid;   // float4 index
    if (i < N_NODES * D / 4) {
        float4 v = ((const float4*)t2)[i];
        int c = (i & (D / 4 - 1)) * 4;
        v.x = fmaxf(0.f, sc[c + 0] * v.x + sh[c + 0]);
        v.y = fmaxf(0.f, sc[c + 1] * v.y + sh[c + 1]);
        v.z = fmaxf(0.f, sc[c + 2] * v.z + sh[c + 2]);
        v.w = fmaxf(0.f, sc[c + 3] * v.w + sh[c + 3]);
        ((float4*)out)[i] = v;
    }
}

extern "C" void kernel_launch(void* const* d_in, const int* in_sizes, int n_in,
                              void* d_out, int out_size, void* d_ws, size_t ws_size,
                              hipStream_t stream) {
    const float* d_h   = (const float*)d_in[0];
    const int*   d_src = (const int*)d_in[1];
    const int*   d_dst = (const int*)d_in[2];
    const float* d_ew  = (const float*)d_in[3];
    const float* d_eps = (const float*)d_in[4];
    const float* d_W1  = (const float*)d_in[5];
    const float* d_b1  = (const float*)d_in[6];
    const float* d_g1  = (const float*)d_in[7];
    const float* d_bt1 = (const float*)d_in[8];
    const float* d_W2  = (const float*)d_in[9];
    const float* d_b2  = (const float*)d_in[10];
    const float* d_g2  = (const float*)d_in[11];
    const float* d_bt2 = (const float*)d_in[12];
    float* out = (float*)d_out;

    char* ws = (char*)d_ws;
    size_t o = 0;
    auto take = [&](size_t bytes) -> char* {
        char* p = ws + o;
        o += (bytes + 255) & ~(size_t)255;
        return p;
    };
    int*            cnt     = (int*)take((N_NODES + 1) * sizeof(int));
    int*            row_ptr = (int*)take((N_NODES + 1) * sizeof(int));
    int*            row_run = (int*)take((N_NODES + 1) * sizeof(int));
    int2*           edata   = (int2*)take(N_EDGES * sizeof(int2));
    unsigned int*   xh      = (unsigned int*)take((size_t)N_NODES * D * 2);
    unsigned int*   xl      = (unsigned int*)take((size_t)N_NODES * D * 2);
    float*          y       = (float*)take((size_t)N_NODES * D * sizeof(float));
    float*          t2      = (float*)take((size_t)N_NODES * D * sizeof(float));
    unsigned short* W1th    = (unsigned short*)take((size_t)NLAYERS * D * D * 2);
    unsigned short* W1tl    = (unsigned short*)take((size_t)NLAYERS * D * D * 2);
    unsigned short* W2th    = (unsigned short*)take((size_t)NLAYERS * D * D * 2);
    unsigned short* W2tl    = (unsigned short*)take((size_t)NLAYERS * D * D * 2);
    float*          stats1  = (float*)take(2 * D * sizeof(float));
    float*          stats2  = (float*)take(2 * D * sizeof(float));
    (void)ws_size; (void)in_sizes; (void)n_in; (void)out_size;

    // CSR build (once per call; dst/src/ew invariant across layers)
    hipMemsetAsync(cnt, 0, (N_NODES + 1) * sizeof(int), stream);
    k_hist<<<N_EDGES / 256, 256, 0, stream>>>(d_dst, cnt);
    k_scan<<<1, 256, 0, stream>>>(cnt, row_ptr, row_run);
    k_scatter<<<N_EDGES / 256, 256, 0, stream>>>(d_src, d_dst, d_ew, row_run, edata);
    k_wconv<<<(NLAYERS * D * D + 255) / 256, 256, 0, stream>>>(d_W1, d_W2, W1th, W1tl, W2th, W2tl);

    for (int l = 0; l < NLAYERS; ++l) {
        if (l == 0) {
            k_agg<0><<<N_NODES / 4, 256, 0, stream>>>(d_h, nullptr, nullptr, nullptr,
                                                      row_ptr, edata, d_eps, l, xh, xl);
        } else {
            k_agg<1><<<N_NODES / 4, 256, 0, stream>>>(t2, stats2, d_g2 + (l - 1) * D,
                                                      d_bt2 + (l - 1) * D,
                                                      row_ptr, edata, d_eps, l, xh, xl);
        }
        hipMemsetAsync(stats1, 0, 2 * D * sizeof(float), stream);
        k_gemm1<<<N_NODES / 64, 256, 0, stream>>>(xh, xl, W1th + l * D * D, W1tl + l * D * D,
                                                  d_b1 + l * D, y);
        k_stats<<<(N_NODES + 127) / 128, 256, 0, stream>>>(y, stats1);
        k_gemm2<<<N_NODES / 64, 256, 0, stream>>>(y, stats1, d_g1 + l * D, d_bt1 + l * D,
                                                  W2th + l * D * D, W2tl + l * D * D,
                                                  d_b2 + l * D, t2);
        hipMemsetAsync(stats2, 0, 2 * D * sizeof(float), stream);
        k_stats<<<(N_NODES + 127) / 128, 256, 0, stream>>>(t2, stats2);
    }
    k_bnout<<<N_NODES * D / 4 / 256, 256, 0, stream>>>(t2, stats2, d_g2 + 2 * D,
                                                       d_bt2 + 2 * D, out);
}

// Round 3
// 553.807 us; speedup vs baseline: 1.3178x; 1.3178x over previous
//
#include <hip/hip_runtime.h>
#include <hip/hip_bf16.h>

#define N_NODES 40000
#define N_EDGES 640000
#define D 128
#define NLAYERS 3
#define BN_EPS 1e-5f
#define NB_SCAN 157   // ceil(40001/256)

using short8 = __attribute__((ext_vector_type(8))) short;
using f32x4  = __attribute__((ext_vector_type(4))) float;

static __device__ __forceinline__ unsigned short f2bf(float f) {
    unsigned u = __float_as_uint(f);
    unsigned r = (u + 0x7fffu + ((u >> 16) & 1u)) >> 16;   // RNE
    return (unsigned short)r;
}
static __device__ __forceinline__ float bf2f(unsigned short h) {
    return __uint_as_float((unsigned)h << 16);
}

// ---------------- CSR build (dst is invariant across layers) ----------------
__global__ void k_hist(const int* __restrict__ dst, int* __restrict__ cnt) {
    int i = blockIdx.x * blockDim.x + threadIdx.x;
    if (i < N_EDGES) atomicAdd(&cnt[dst[i]], 1);
}

// block partial sums of cnt
__global__ __launch_bounds__(256) void k_part(const int* __restrict__ cnt,
                                              int* __restrict__ part) {
    __shared__ int sred[256];
    int t = threadIdx.x;
    int idx = blockIdx.x * 256 + t;
    int v = (idx < N_NODES) ? cnt[idx] : 0;
    sred[t] = v;
    __syncthreads();
    #pragma unroll
    for (int off = 128; off > 0; off >>= 1) {
        if (t < off) sred[t] += sred[t + off];
        __syncthreads();
    }
    if (t == 0) part[blockIdx.x] = sred[0];
}

// exclusive scan of the 157 partials (single block)
__global__ __launch_bounds__(256) void k_scanpart(const int* __restrict__ part,
                                                  int* __restrict__ pbase) {
    __shared__ int s[256];
    int t = threadIdx.x;
    int v = (t < NB_SCAN) ? part[t] : 0;
    s[t] = v;
    __syncthreads();
    #pragma unroll
    for (int off = 1; off < 256; off <<= 1) {
        int x = (t >= off) ? s[t - off] : 0;
        __syncthreads();
        s[t] += x;
        __syncthreads();
    }
    pbase[t] = s[t] - v;   // exclusive
}

// emit row_ptr / row_run: exclusive scan within chunk + chunk base
__global__ __launch_bounds__(256) void k_emit(const int* __restrict__ cnt,
                                              const int* __restrict__ pbase,
                                              int* __restrict__ row_ptr,
                                              int* __restrict__ row_run) {
    __shared__ int s[256];
    int t = threadIdx.x;
    int idx = blockIdx.x * 256 + t;
    int v = (idx < N_NODES) ? cnt[idx] : 0;
    s[t] = v;
    __syncthreads();
    #pragma unroll
    for (int off = 1; off < 256; off <<= 1) {
        int x = (t >= off) ? s[t - off] : 0;
        __syncthreads();
        s[t] += x;
        __syncthreads();
    }
    int r = pbase[blockIdx.x] + s[t] - v;   // exclusive prefix
    if (idx < N_NODES) { row_ptr[idx] = r; row_run[idx] = r; }
    else if (idx == N_NODES) row_ptr[idx] = r;
}

__global__ void k_scatter(const int* __restrict__ src, const int* __restrict__ dst,
                          const float* __restrict__ ew, int* __restrict__ row_run,
                          int2* __restrict__ edata) {
    int i = blockIdx.x * blockDim.x + threadIdx.x;
    if (i < N_EDGES) {
        int d = dst[i];
        int pos = atomicAdd(&row_run[d], 1);
        edata[pos] = make_int2(src[i], __float_as_int(ew[i]));
    }
}

// -------- weight transpose + bf16 hi/lo convert (once); also zeros cnt --------
__global__ void k_wconv(const float* __restrict__ W1, const float* __restrict__ W2,
                        unsigned short* __restrict__ W1th, unsigned short* __restrict__ W1tl,
                        unsigned short* __restrict__ W2th, unsigned short* __restrict__ W2tl,
                        int* __restrict__ cnt) {
    int i = blockIdx.x * blockDim.x + threadIdx.x;   // grid exactly NLAYERS*D*D = 49152
    if (i <= N_NODES) cnt[i] = 0;                    // runs before k_hist in stream order
    int l = i / (D * D);
    int r = i % (D * D);
    int k = r / D, c = r % D;
    int oidx = l * D * D + c * D + k;
    float w1 = W1[l * D * D + k * D + c];
    unsigned short h1 = f2bf(w1);
    W1th[oidx] = h1;
    W1tl[oidx] = f2bf(w1 - bf2f(h1));
    float w2 = W2[l * D * D + k * D + c];
    unsigned short h2 = f2bf(w2);
    W2th[oidx] = h2;
    W2tl[oidx] = f2bf(w2 - bf2f(h2));
}

// -------- aggregation: x = (1+eps)*h + sum_e ew*h[src], h = relu(bn(prev)) fused --------
// outputs x as hi/lo bf16 planes; block 0 zeros stats1 (accumulated by following gemm1)
template <int USE_BN>
__global__ __launch_bounds__(256) void k_agg(
        const float* __restrict__ hin, const float* __restrict__ stats,
        const float* __restrict__ gamma, const float* __restrict__ beta,
        const int* __restrict__ row_ptr, const int2* __restrict__ edata,
        const float* __restrict__ eps_list, int layer,
        unsigned int* __restrict__ xh, unsigned int* __restrict__ xl,
        float* __restrict__ stats1) {
    __shared__ float sc[D], sh[D];
    int tid = threadIdx.x;
    if (blockIdx.x == 0 && tid < 2 * D) stats1[tid] = 0.f;
    if (USE_BN) {
        if (tid < D) {
            float s = stats[tid], q = stats[D + tid];
            float mean = s * (1.0f / N_NODES);
            float var  = q * (1.0f / N_NODES) - mean * mean;
            float inv  = rsqrtf(var + BN_EPS);
            float scale = gamma[tid] * inv;
            sc[tid] = scale;
            sh[tid] = beta[tid] - mean * scale;
        }
        __syncthreads();
    }
    int wv = tid >> 6, lane = tid & 63;
    int node = blockIdx.x * 4 + wv;   // grid = N_NODES/4 exactly

    float sc0 = 1.f, sh0 = 0.f, sc1 = 1.f, sh1 = 0.f;
    if (USE_BN) { sc0 = sc[2 * lane]; sh0 = sh[2 * lane]; sc1 = sc[2 * lane + 1]; sh1 = sh[2 * lane + 1]; }

    const float2* h2 = (const float2*)hin;
    float2 acc = make_float2(0.f, 0.f);
    int e = row_ptr[node], end = row_ptr[node + 1];
    for (; e + 1 < end; e += 2) {
        int2 e0 = edata[e], e1 = edata[e + 1];
        float2 v0 = h2[e0.x * 64 + lane];
        float2 v1 = h2[e1.x * 64 + lane];
        float w0 = __int_as_float(e0.y), w1 = __int_as_float(e1.y);
        if (USE_BN) {
            v0.x = fmaxf(0.f, sc0 * v0.x + sh0); v0.y = fmaxf(0.f, sc1 * v0.y + sh1);
            v1.x = fmaxf(0.f, sc0 * v1.x + sh0); v1.y = fmaxf(0.f, sc1 * v1.y + sh1);
        }
        acc.x = fmaf(w0, v0.x, acc.x); acc.y = fmaf(w0, v0.y, acc.y);
        acc.x = fmaf(w1, v1.x, acc.x); acc.y = fmaf(w1, v1.y, acc.y);
    }
    if (e < end) {
        int2 e0 = edata[e];
        float2 v0 = h2[e0.x * 64 + lane];
        float w0 = __int_as_float(e0.y);
        if (USE_BN) {
            v0.x = fmaxf(0.f, sc0 * v0.x + sh0); v0.y = fmaxf(0.f, sc1 * v0.y + sh1);
        }
        acc.x = fmaf(w0, v0.x, acc.x); acc.y = fmaf(w0, v0.y, acc.y);
    }
    float2 hv = h2[node * 64 + lane];
    if (USE_BN) {
        hv.x = fmaxf(0.f, sc0 * hv.x + sh0); hv.y = fmaxf(0.f, sc1 * hv.y + sh1);
    }
    float ep = 1.0f + eps_list[layer];
    float x0 = fmaf(ep, hv.x, acc.x);
    float x1 = fmaf(ep, hv.y, acc.y);
    unsigned short h0 = f2bf(x0), h1 = f2bf(x1);
    unsigned short l0 = f2bf(x0 - bf2f(h0)), l1 = f2bf(x1 - bf2f(h1));
    xh[node * 64 + lane] = (unsigned)h0 | ((unsigned)h1 << 16);
    xl[node * 64 + lane] = (unsigned)l0 | ((unsigned)l1 << 16);
}

// ------- GEMM1: y = x @ W1t + b1 (split-bf16); fused column stats -> stats1; zeros stats2 -------
__global__ __launch_bounds__(256) void k_gemm1(
        const unsigned int* __restrict__ xh, const unsigned int* __restrict__ xl,
        const unsigned short* __restrict__ Wth, const unsigned short* __restrict__ Wtl,
        const float* __restrict__ b1, float* __restrict__ y,
        float* __restrict__ stats1, float* __restrict__ stats2) {
    __shared__ float cs[D], cq[D];
    int tid = threadIdx.x;
    if (blockIdx.x == 0 && tid < 2 * D) stats2[tid] = 0.f;
    if (tid < D) { cs[tid] = 0.f; cq[tid] = 0.f; }
    __syncthreads();

    int wv = tid >> 6, lane = tid & 63;
    int lr = lane & 15, lk = lane >> 4;
    int rowBase = blockIdx.x * 64 + wv * 16;
    f32x4 acc[8];
    #pragma unroll
    for (int nt = 0; nt < 8; ++nt) acc[nt] = (f32x4){0.f, 0.f, 0.f, 0.f};

    const short8* xrowh = (const short8*)((const unsigned short*)xh + (rowBase + lr) * D);
    const short8* xrowl = (const short8*)((const unsigned short*)xl + (rowBase + lr) * D);
    #pragma unroll
    for (int kk = 0; kk < 4; ++kk) {
        short8 ah = xrowh[kk * 4 + lk];
        short8 al = xrowl[kk * 4 + lk];
        #pragma unroll
        for (int nt = 0; nt < 8; ++nt) {
            const short8* wrowh = (const short8*)(Wth + (nt * 16 + lr) * D);
            const short8* wrowl = (const short8*)(Wtl + (nt * 16 + lr) * D);
            short8 bh = wrowh[kk * 4 + lk];
            short8 bl = wrowl[kk * 4 + lk];
            acc[nt] = __builtin_amdgcn_mfma_f32_16x16x32_bf16(ah, bh, acc[nt], 0, 0, 0);
            acc[nt] = __builtin_amdgcn_mfma_f32_16x16x32_bf16(ah, bl, acc[nt], 0, 0, 0);
            acc[nt] = __builtin_amdgcn_mfma_f32_16x16x32_bf16(al, bh, acc[nt], 0, 0, 0);
        }
    }
    #pragma unroll
    for (int nt = 0; nt < 8; ++nt) {
        int col = nt * 16 + lr;
        float bias = b1[col];
        float s = 0.f, q = 0.f;
        #pragma unroll
        for (int j = 0; j < 4; ++j) {
            int row = rowBase + lk * 4 + j;
            float v = acc[nt][j] + bias;
            y[row * D + col] = v;
            s += v; q += v * v;
        }
        s += __shfl_xor(s, 16); q += __shfl_xor(q, 16);
        s += __shfl_xor(s, 32); q += __shfl_xor(q, 32);
        if (lk == 0) { atomicAdd(&cs[col], s); atomicAdd(&cq[col], q); }
    }
    __syncthreads();
    if (tid < D) {
        atomicAdd(&stats1[tid], cs[tid]);
        atomicAdd(&stats1[D + tid], cq[tid]);
    }
}

// ---- GEMM2: t2 = relu(relu(bn1(y)) @ W2t + b2) (split-bf16); fused column stats -> stats2 ----
__global__ __launch_bounds__(256) void k_gemm2(
        const float* __restrict__ y, const float* __restrict__ stats1,
        const float* __restrict__ g1, const float* __restrict__ bt1,
        const unsigned short* __restrict__ Wth, const unsigned short* __restrict__ Wtl,
        const float* __restrict__ b2, float* __restrict__ t2,
        float* __restrict__ stats2) {
    __shared__ float sc[D], sh[D], cs[D], cq[D];
    int tid = threadIdx.x;
    if (tid < D) {
        float s = stats1[tid], q = stats1[D + tid];
        float mean = s * (1.0f / N_NODES);
        float var  = q * (1.0f / N_NODES) - mean * mean;
        float inv  = rsqrtf(var + BN_EPS);
        float scale = g1[tid] * inv;
        sc[tid] = scale;
        sh[tid] = bt1[tid] - mean * scale;
        cs[tid] = 0.f; cq[tid] = 0.f;
    }
    __syncthreads();

    int wv = tid >> 6, lane = tid & 63;
    int lr = lane & 15, lk = lane >> 4;
    int rowBase = blockIdx.x * 64 + wv * 16;
    f32x4 acc[8];
    #pragma unroll
    for (int nt = 0; nt < 8; ++nt) acc[nt] = (f32x4){0.f, 0.f, 0.f, 0.f};

    const float* yrow = y + (rowBase + lr) * D;
    #pragma unroll
    for (int kk = 0; kk < 4; ++kk) {
        int k0 = kk * 32 + lk * 8;
        float vv[8];
        *(float4*)&vv[0] = *(const float4*)(yrow + k0);
        *(float4*)&vv[4] = *(const float4*)(yrow + k0 + 4);
        short8 ah, al;
        #pragma unroll
        for (int i = 0; i < 8; ++i) {
            float t = fmaxf(0.f, sc[k0 + i] * vv[i] + sh[k0 + i]);
            unsigned short hi = f2bf(t);
            ah[i] = (short)hi;
            al[i] = (short)f2bf(t - bf2f(hi));
        }
        #pragma unroll
        for (int nt = 0; nt < 8; ++nt) {
            const short8* wrowh = (const short8*)(Wth + (nt * 16 + lr) * D);
            const short8* wrowl = (const short8*)(Wtl + (nt * 16 + lr) * D);
            short8 bh = wrowh[kk * 4 + lk];
            short8 bl = wrowl[kk * 4 + lk];
            acc[nt] = __builtin_amdgcn_mfma_f32_16x16x32_bf16(ah, bh, acc[nt], 0, 0, 0);
            acc[nt] = __builtin_amdgcn_mfma_f32_16x16x32_bf16(ah, bl, acc[nt], 0, 0, 0);
            acc[nt] = __builtin_amdgcn_mfma_f32_16x16x32_bf16(al, bh, acc[nt], 0, 0, 0);
        }
    }
    #pragma unroll
    for (int nt = 0; nt < 8; ++nt) {
        int col = nt * 16 + lr;
        float bias = b2[col];
        float s = 0.f, q = 0.f;
        #pragma unroll
        for (int j = 0; j < 4; ++j) {
            int row = rowBase + lk * 4 + j;
            float v = fmaxf(0.f, acc[nt][j] + bias);
            t2[row * D + col] = v;
            s += v; q += v * v;
        }
        s += __shfl_xor(s, 16); q += __shfl_xor(q, 16);
        s += __shfl_xor(s, 32); q += __shfl_xor(q, 32);
        if (lk == 0) { atomicAdd(&cs[col], s); atomicAdd(&cq[col], q); }
    }
    __syncthreads();
    if (tid < D) {
        atomicAdd(&stats2[tid], cs[tid]);
        atomicAdd(&stats2[D + tid], cq[tid]);
    }
}

// ---------------- final output: out = relu(bn2(t2)) ----------------
__global__ __launch_bounds__(256) void k_bnout(
        const float* __restrict__ t2, const float* __restrict__ stats,
        const float* __restrict__ gamma, const float* __restrict__ beta,
        float* __restrict__ out) {
    __shared__ float sc[D], sh[D];
    int tid = threadIdx.x;
    if (tid < D) {
        float s = stats[tid], q = stats[D + tid];
        float mean = s * (1.0f / N_NODES);
        float var  = q * (1.0f / N_NODES) - mean * mean;
        float inv  = rsqrtf(var + BN_EPS);
        float scale = gamma[tid] * inv;
        sc[tid] = scale;
        sh[tid] = beta[tid] - mean * scale;
    }
    __syncthreads();
    int i = blockIdx.x * blockDim.x + tid;   // float4 index
    if (i < N_NODES * D / 4) {
        float4 v = ((const float4*)t2)[i];
        int c = (i & (D / 4 - 1)) * 4;
        v.x = fmaxf(0.f, sc[c + 0] * v.x + sh[c + 0]);
        v.y = fmaxf(0.f, sc[c + 1] * v.y + sh[c + 1]);
        v.z = fmaxf(0.f, sc[c + 2] * v.z + sh[c + 2]);
        v.w = fmaxf(0.f, sc[c + 3] * v.w + sh[c + 3]);
        ((float4*)out)[i] = v;
    }
}

extern "C" void kernel_launch(void* const* d_in, const int* in_sizes, int n_in,
                              void* d_out, int out_size, void* d_ws, size_t ws_size,
                              hipStream_t stream) {
    const float* d_h   = (const float*)d_in[0];
    const int*   d_src = (const int*)d_in[1];
    const int*   d_dst = (const int*)d_in[2];
    const float* d_ew  = (const float*)d_in[3];
    const float* d_eps = (const float*)d_in[4];
    const float* d_W1  = (const float*)d_in[5];
    const float* d_b1  = (const float*)d_in[6];
    const float* d_g1  = (const float*)d_in[7];
    const float* d_bt1 = (const float*)d_in[8];
    const float* d_W2  = (const float*)d_in[9];
    const float* d_b2  = (const float*)d_in[10];
    const float* d_g2  = (const float*)d_in[11];
    const float* d_bt2 = (const float*)d_in[12];
    float* out = (float*)d_out;

    char* ws = (char*)d_ws;
    size_t o = 0;
    auto take = [&](size_t bytes) -> char* {
        char* p = ws + o;
        o += (bytes + 255) & ~(size_t)255;
        return p;
    };
    int*            cnt     = (int*)take((N_NODES + 1) * sizeof(int));
    int*            row_ptr = (int*)take((N_NODES + 1) * sizeof(int));
    int*            row_run = (int*)take((N_NODES + 1) * sizeof(int));
    int*            part    = (int*)take(256 * sizeof(int));
    int*            pbase   = (int*)take(256 * sizeof(int));
    int2*           edata   = (int2*)take(N_EDGES * sizeof(int2));
    unsigned int*   xh      = (unsigned int*)take((size_t)N_NODES * D * 2);
    unsigned int*   xl      = (unsigned int*)take((size_t)N_NODES * D * 2);
    float*          y       = (float*)take((size_t)N_NODES * D * sizeof(float));
    float*          t2      = (float*)take((size_t)N_NODES * D * sizeof(float));
    unsigned short* W1th    = (unsigned short*)take((size_t)NLAYERS * D * D * 2);
    unsigned short* W1tl    = (unsigned short*)take((size_t)NLAYERS * D * D * 2);
    unsigned short* W2th    = (unsigned short*)take((size_t)NLAYERS * D * D * 2);
    unsigned short* W2tl    = (unsigned short*)take((size_t)NLAYERS * D * D * 2);
    float*          stats1  = (float*)take(2 * D * sizeof(float));
    float*          stats2  = (float*)take(2 * D * sizeof(float));
    (void)ws_size; (void)in_sizes; (void)n_in; (void)out_size;

    // CSR build (dst/src/ew invariant across layers). k_wconv also zeros cnt.
    k_wconv<<<NLAYERS * D * D / 256, 256, 0, stream>>>(d_W1, d_W2, W1th, W1tl, W2th, W2tl, cnt);
    k_hist<<<N_EDGES / 256, 256, 0, stream>>>(d_dst, cnt);
    k_part<<<NB_SCAN, 256, 0, stream>>>(cnt, part);
    k_scanpart<<<1, 256, 0, stream>>>(part, pbase);
    k_emit<<<NB_SCAN, 256, 0, stream>>>(cnt, pbase, row_ptr, row_run);
    k_scatter<<<N_EDGES / 256, 256, 0, stream>>>(d_src, d_dst, d_ew, row_run, edata);

    for (int l = 0; l < NLAYERS; ++l) {
        if (l == 0) {
            k_agg<0><<<N_NODES / 4, 256, 0, stream>>>(d_h, nullptr, nullptr, nullptr,
                                                      row_ptr, edata, d_eps, l, xh, xl, stats1);
        } else {
            k_agg<1><<<N_NODES / 4, 256, 0, stream>>>(t2, stats2, d_g2 + (l - 1) * D,
                                                      d_bt2 + (l - 1) * D,
                                                      row_ptr, edata, d_eps, l, xh, xl, stats1);
        }
        k_gemm1<<<N_NODES / 64, 256, 0, stream>>>(xh, xl, W1th + l * D * D, W1tl + l * D * D,
                                                  d_b1 + l * D, y, stats1, stats2);
        k_gemm2<<<N_NODES / 64, 256, 0, stream>>>(y, stats1, d_g1 + l * D, d_bt1 + l * D,
                                                  W2th + l * D * D, W2tl + l * D * D,
                                                  d_b2 + l * D, t2, stats2);
    }
    k_bnout<<<N_NODES * D / 4 / 256, 256, 0, stream>>>(t2, stats2, d_g2 + 2 * D,
                                                       d_bt2 + 2 * D, out);
}

// Round 5
// 507.600 us; speedup vs baseline: 1.4378x; 1.0910x over previous
//
#include <hip/hip_runtime.h>
#include <hip/hip_bf16.h>

#define N_NODES 40000
#define N_EDGES 640000
#define D 128
#define NLAYERS 3
#define BN_EPS 1e-5f
#define NB_SCAN 157   // ceil(40001/256)

using short8 = __attribute__((ext_vector_type(8))) short;
using f32x4  = __attribute__((ext_vector_type(4))) float;

static __device__ __forceinline__ unsigned short f2bf(float f) {
    unsigned u = __float_as_uint(f);
    unsigned r = (u + 0x7fffu + ((u >> 16) & 1u)) >> 16;   // RNE
    return (unsigned short)r;
}
static __device__ __forceinline__ float bf2f(unsigned short h) {
    return __uint_as_float((unsigned)h << 16);
}
static __device__ __forceinline__ float2 up2(unsigned u) {
    return make_float2(bf2f((unsigned short)(u & 0xffffu)),
                       bf2f((unsigned short)(u >> 16)));
}

// ---------------- CSR build (dst is invariant across layers) ----------------
__global__ void k_hist(const int* __restrict__ dst, int* __restrict__ cnt) {
    int i = blockIdx.x * blockDim.x + threadIdx.x;
    if (i < N_EDGES) atomicAdd(&cnt[dst[i]], 1);
}

__global__ __launch_bounds__(256) void k_part(const int* __restrict__ cnt,
                                              int* __restrict__ part) {
    __shared__ int sred[256];
    int t = threadIdx.x;
    int idx = blockIdx.x * 256 + t;
    int v = (idx < N_NODES) ? cnt[idx] : 0;
    sred[t] = v;
    __syncthreads();
    #pragma unroll
    for (int off = 128; off > 0; off >>= 1) {
        if (t < off) sred[t] += sred[t + off];
        __syncthreads();
    }
    if (t == 0) part[blockIdx.x] = sred[0];
}

__global__ __launch_bounds__(256) void k_scanpart(const int* __restrict__ part,
                                                  int* __restrict__ pbase) {
    __shared__ int s[256];
    int t = threadIdx.x;
    int v = (t < NB_SCAN) ? part[t] : 0;
    s[t] = v;
    __syncthreads();
    #pragma unroll
    for (int off = 1; off < 256; off <<= 1) {
        int x = (t >= off) ? s[t - off] : 0;
        __syncthreads();
        s[t] += x;
        __syncthreads();
    }
    pbase[t] = s[t] - v;   // exclusive
}

__global__ __launch_bounds__(256) void k_emit(const int* __restrict__ cnt,
                                              const int* __restrict__ pbase,
                                              int* __restrict__ row_ptr,
                                              int* __restrict__ row_run) {
    __shared__ int s[256];
    int t = threadIdx.x;
    int idx = blockIdx.x * 256 + t;
    int v = (idx < N_NODES) ? cnt[idx] : 0;
    s[t] = v;
    __syncthreads();
    #pragma unroll
    for (int off = 1; off < 256; off <<= 1) {
        int x = (t >= off) ? s[t - off] : 0;
        __syncthreads();
        s[t] += x;
        __syncthreads();
    }
    int r = pbase[blockIdx.x] + s[t] - v;   // exclusive prefix
    if (idx < N_NODES) { row_ptr[idx] = r; row_run[idx] = r; }
    else if (idx == N_NODES) row_ptr[idx] = r;
}

__global__ void k_scatter(const int* __restrict__ src, const int* __restrict__ dst,
                          const float* __restrict__ ew, int* __restrict__ row_run,
                          int2* __restrict__ edata) {
    int i = blockIdx.x * blockDim.x + threadIdx.x;
    if (i < N_EDGES) {
        int d = dst[i];
        int pos = atomicAdd(&row_run[d], 1);
        edata[pos] = make_int2(src[i], __float_as_int(ew[i]));
    }
}

// -------- weight transpose + bf16 hi/lo convert (once); also zeros cnt --------
__global__ void k_wconv(const float* __restrict__ W1, const float* __restrict__ W2,
                        unsigned short* __restrict__ W1th, unsigned short* __restrict__ W1tl,
                        unsigned short* __restrict__ W2th, unsigned short* __restrict__ W2tl,
                        int* __restrict__ cnt) {
    int i = blockIdx.x * blockDim.x + threadIdx.x;   // grid exactly NLAYERS*D*D = 49152
    if (i <= N_NODES) cnt[i] = 0;                    // runs before k_hist in stream order
    int l = i / (D * D);
    int r = i % (D * D);
    int k = r / D, c = r % D;
    int oidx = l * D * D + c * D + k;
    float w1 = W1[l * D * D + k * D + c];
    unsigned short h1 = f2bf(w1);
    W1th[oidx] = h1;
    W1tl[oidx] = f2bf(w1 - bf2f(h1));
    float w2 = W2[l * D * D + k * D + c];
    unsigned short h2 = f2bf(w2);
    W2th[oidx] = h2;
    W2tl[oidx] = f2bf(w2 - bf2f(h2));
}

// ---------------- h (fp32) -> packed bf16 rows, layer-0 gather source ----------------
__global__ __launch_bounds__(256) void k_h2b(const float* __restrict__ h,
                                             unsigned int* __restrict__ hb) {
    int i = blockIdx.x * 256 + threadIdx.x;   // uint index; grid covers N*D/2 exactly
    float2 v = ((const float2*)h)[i];
    hb[i] = (unsigned)f2bf(v.x) | ((unsigned)f2bf(v.y) << 16);
}

// -------- aggregation: x = (1+eps)*h + sum_e ew*h[src]; h = relu(bn(hb)) fused --------
// hb: packed-bf16 rows [N][64]. Outputs x as hi/lo bf16 planes; block 0 zeros stats1.
template <int USE_BN>
__global__ __launch_bounds__(256) void k_agg(
        const unsigned int* __restrict__ hb, const float* __restrict__ stats,
        const float* __restrict__ gamma, const float* __restrict__ beta,
        const int* __restrict__ row_ptr, const int2* __restrict__ edata,
        const float* __restrict__ eps_list, int layer,
        unsigned int* __restrict__ xh, unsigned int* __restrict__ xl,
        float* __restrict__ stats1) {
    __shared__ float sc[D], sh[D];
    int tid = threadIdx.x;
    if (blockIdx.x == 0 && tid < 2 * D) stats1[tid] = 0.f;
    if (USE_BN) {
        if (tid < D) {
            float s = stats[tid], q = stats[D + tid];
            float mean = s * (1.0f / N_NODES);
            float var  = q * (1.0f / N_NODES) - mean * mean;
            float inv  = rsqrtf(var + BN_EPS);
            float scale = gamma[tid] * inv;
            sc[tid] = scale;
            sh[tid] = beta[tid] - mean * scale;
        }
        __syncthreads();
    }
    int wv = tid >> 6, lane = tid & 63;
    int node = blockIdx.x * 4 + wv;   // grid = N_NODES/4 exactly

    float sc0 = 1.f, sh0 = 0.f, sc1 = 1.f, sh1 = 0.f;
    if (USE_BN) { sc0 = sc[2 * lane]; sh0 = sh[2 * lane]; sc1 = sc[2 * lane + 1]; sh1 = sh[2 * lane + 1]; }

    float2 acc = make_float2(0.f, 0.f);
    int e = row_ptr[node], end = row_ptr[node + 1];

    #define PROC(q, u)                                                        \
        {                                                                     \
            float2 v = up2(u);                                                \
            if (USE_BN) {                                                     \
                v.x = fmaxf(0.f, sc0 * v.x + sh0);                            \
                v.y = fmaxf(0.f, sc1 * v.y + sh1);                            \
            }                                                                 \
            float w = __int_as_float((q).y);                                  \
            acc.x = fmaf(w, v.x, acc.x);                                      \
            acc.y = fmaf(w, v.y, acc.y);                                      \
        }

    for (; e + 3 < end; e += 4) {
        int2 q0 = edata[e], q1 = edata[e + 1], q2 = edata[e + 2], q3 = edata[e + 3];
        unsigned u0 = hb[q0.x * 64 + lane];
        unsigned u1 = hb[q1.x * 64 + lane];
        unsigned u2 = hb[q2.x * 64 + lane];
        unsigned u3 = hb[q3.x * 64 + lane];
        PROC(q0, u0) PROC(q1, u1) PROC(q2, u2) PROC(q3, u3)
    }
    for (; e < end; ++e) {
        int2 q0 = edata[e];
        unsigned u0 = hb[q0.x * 64 + lane];
        PROC(q0, u0)
    }
    #undef PROC

    unsigned su = hb[node * 64 + lane];
    float2 hv = up2(su);
    if (USE_BN) {
        hv.x = fmaxf(0.f, sc0 * hv.x + sh0);
        hv.y = fmaxf(0.f, sc1 * hv.y + sh1);
    }
    float ep = 1.0f + eps_list[layer];
    float x0 = fmaf(ep, hv.x, acc.x);
    float x1 = fmaf(ep, hv.y, acc.y);
    unsigned short h0 = f2bf(x0), h1 = f2bf(x1);
    unsigned short l0 = f2bf(x0 - bf2f(h0)), l1 = f2bf(x1 - bf2f(h1));
    xh[node * 64 + lane] = (unsigned)h0 | ((unsigned)h1 << 16);
    xl[node * 64 + lane] = (unsigned)l0 | ((unsigned)l1 << 16);
}

// ------- GEMM1: y = x @ W1t + b1 (split-bf16); fused column stats -> stats1; zeros stats2 -------
__global__ __launch_bounds__(256) void k_gemm1(
        const unsigned int* __restrict__ xh, const unsigned int* __restrict__ xl,
        const unsigned short* __restrict__ Wth, const unsigned short* __restrict__ Wtl,
        const float* __restrict__ b1, float* __restrict__ y,
        float* __restrict__ stats1, float* __restrict__ stats2) {
    __shared__ float cs[D], cq[D];
    int tid = threadIdx.x;
    if (blockIdx.x == 0 && tid < 2 * D) stats2[tid] = 0.f;
    if (tid < D) { cs[tid] = 0.f; cq[tid] = 0.f; }
    __syncthreads();

    int wv = tid >> 6, lane = tid & 63;
    int lr = lane & 15, lk = lane >> 4;
    int rowBase = blockIdx.x * 64 + wv * 16;
    f32x4 acc[8];
    #pragma unroll
    for (int nt = 0; nt < 8; ++nt) acc[nt] = (f32x4){0.f, 0.f, 0.f, 0.f};

    const short8* xrowh = (const short8*)((const unsigned short*)xh + (rowBase + lr) * D);
    const short8* xrowl = (const short8*)((const unsigned short*)xl + (rowBase + lr) * D);
    #pragma unroll
    for (int kk = 0; kk < 4; ++kk) {
        short8 ah = xrowh[kk * 4 + lk];
        short8 al = xrowl[kk * 4 + lk];
        #pragma unroll
        for (int nt = 0; nt < 8; ++nt) {
            const short8* wrowh = (const short8*)(Wth + (nt * 16 + lr) * D);
            const short8* wrowl = (const short8*)(Wtl + (nt * 16 + lr) * D);
            short8 bh = wrowh[kk * 4 + lk];
            short8 bl = wrowl[kk * 4 + lk];
            acc[nt] = __builtin_amdgcn_mfma_f32_16x16x32_bf16(ah, bh, acc[nt], 0, 0, 0);
            acc[nt] = __builtin_amdgcn_mfma_f32_16x16x32_bf16(ah, bl, acc[nt], 0, 0, 0);
            acc[nt] = __builtin_amdgcn_mfma_f32_16x16x32_bf16(al, bh, acc[nt], 0, 0, 0);
        }
    }
    #pragma unroll
    for (int nt = 0; nt < 8; ++nt) {
        int col = nt * 16 + lr;
        float bias = b1[col];
        float s = 0.f, q = 0.f;
        #pragma unroll
        for (int j = 0; j < 4; ++j) {
            int row = rowBase + lk * 4 + j;
            float v = acc[nt][j] + bias;
            y[row * D + col] = v;
            s += v; q += v * v;
        }
        s += __shfl_xor(s, 16); q += __shfl_xor(q, 16);
        s += __shfl_xor(s, 32); q += __shfl_xor(q, 32);
        if (lk == 0) { atomicAdd(&cs[col], s); atomicAdd(&cq[col], q); }
    }
    __syncthreads();
    if (tid < D) {
        atomicAdd(&stats1[tid], cs[tid]);
        atomicAdd(&stats1[D + tid], cq[tid]);
    }
}

// ---- GEMM2: t2 = relu(relu(bn1(y)) @ W2t + b2), stored bf16; fused stats -> stats2 ----
__global__ __launch_bounds__(256) void k_gemm2(
        const float* __restrict__ y, const float* __restrict__ stats1,
        const float* __restrict__ g1, const float* __restrict__ bt1,
        const unsigned short* __restrict__ Wth, const unsigned short* __restrict__ Wtl,
        const float* __restrict__ b2, unsigned short* __restrict__ t2b,
        float* __restrict__ stats2) {
    __shared__ float sc[D], sh[D], cs[D], cq[D];
    int tid = threadIdx.x;
    if (tid < D) {
        float s = stats1[tid], q = stats1[D + tid];
        float mean = s * (1.0f / N_NODES);
        float var  = q * (1.0f / N_NODES) - mean * mean;
        float inv  = rsqrtf(var + BN_EPS);
        float scale = g1[tid] * inv;
        sc[tid] = scale;
        sh[tid] = bt1[tid] - mean * scale;
        cs[tid] = 0.f; cq[tid] = 0.f;
    }
    __syncthreads();

    int wv = tid >> 6, lane = tid & 63;
    int lr = lane & 15, lk = lane >> 4;
    int rowBase = blockIdx.x * 64 + wv * 16;
    f32x4 acc[8];
    #pragma unroll
    for (int nt = 0; nt < 8; ++nt) acc[nt] = (f32x4){0.f, 0.f, 0.f, 0.f};

    const float* yrow = y + (rowBase + lr) * D;
    #pragma unroll
    for (int kk = 0; kk < 4; ++kk) {
        int k0 = kk * 32 + lk * 8;
        float vv[8];
        *(float4*)&vv[0] = *(const float4*)(yrow + k0);
        *(float4*)&vv[4] = *(const float4*)(yrow + k0 + 4);
        short8 ah, al;
        #pragma unroll
        for (int i = 0; i < 8; ++i) {
            float t = fmaxf(0.f, sc[k0 + i] * vv[i] + sh[k0 + i]);
            unsigned short hi = f2bf(t);
            ah[i] = (short)hi;
            al[i] = (short)f2bf(t - bf2f(hi));
        }
        #pragma unroll
        for (int nt = 0; nt < 8; ++nt) {
            const short8* wrowh = (const short8*)(Wth + (nt * 16 + lr) * D);
            const short8* wrowl = (const short8*)(Wtl + (nt * 16 + lr) * D);
            short8 bh = wrowh[kk * 4 + lk];
            short8 bl = wrowl[kk * 4 + lk];
            acc[nt] = __builtin_amdgcn_mfma_f32_16x16x32_bf16(ah, bh, acc[nt], 0, 0, 0);
            acc[nt] = __builtin_amdgcn_mfma_f32_16x16x32_bf16(ah, bl, acc[nt], 0, 0, 0);
            acc[nt] = __builtin_amdgcn_mfma_f32_16x16x32_bf16(al, bh, acc[nt], 0, 0, 0);
        }
    }
    #pragma unroll
    for (int nt = 0; nt < 8; ++nt) {
        int col = nt * 16 + lr;
        float bias = b2[col];
        float s = 0.f, q = 0.f;
        #pragma unroll
        for (int j = 0; j < 4; ++j) {
            int row = rowBase + lk * 4 + j;
            float v = fmaxf(0.f, acc[nt][j] + bias);
            t2b[row * D + col] = f2bf(v);
            s += v; q += v * v;
        }
        s += __shfl_xor(s, 16); q += __shfl_xor(q, 16);
        s += __shfl_xor(s, 32); q += __shfl_xor(q, 32);
        if (lk == 0) { atomicAdd(&cs[col], s); atomicAdd(&cq[col], q); }
    }
    __syncthreads();
    if (tid < D) {
        atomicAdd(&stats2[tid], cs[tid]);
        atomicAdd(&stats2[D + tid], cq[tid]);
    }
}

// ---------------- final output: out = relu(bn2(t2b)) ----------------
__global__ __launch_bounds__(256) void k_bnout(
        const unsigned int* __restrict__ t2b, const float* __restrict__ stats,
        const float* __restrict__ gamma, const float* __restrict__ beta,
        float* __restrict__ out) {
    __shared__ float sc[D], sh[D];
    int tid = threadIdx.x;
    if (tid < D) {
        float s = stats[tid], q = stats[D + tid];
        float mean = s * (1.0f / N_NODES);
        float var  = q * (1.0f / N_NODES) - mean * mean;
        float inv  = rsqrtf(var + BN_EPS);
        float scale = gamma[tid] * inv;
        sc[tid] = scale;
        sh[tid] = beta[tid] - mean * scale;
    }
    __syncthreads();
    int i = blockIdx.x * 256 + tid;   // uint index over N*D/2; grid exact
    unsigned u = t2b[i];
    int c = (i & 63) * 2;
    float2 v = up2(u);
    v.x = fmaxf(0.f, sc[c + 0] * v.x + sh[c + 0]);
    v.y = fmaxf(0.f, sc[c + 1] * v.y + sh[c + 1]);
    ((float2*)out)[i] = v;
}

extern "C" void kernel_launch(void* const* d_in, const int* in_sizes, int n_in,
                              void* d_out, int out_size, void* d_ws, size_t ws_size,
                              hipStream_t stream) {
    const float* d_h   = (const float*)d_in[0];
    const int*   d_src = (const int*)d_in[1];
    const int*   d_dst = (const int*)d_in[2];
    const float* d_ew  = (const float*)d_in[3];
    const float* d_eps = (const float*)d_in[4];
    const float* d_W1  = (const float*)d_in[5];
    const float* d_b1  = (const float*)d_in[6];
    const float* d_g1  = (const float*)d_in[7];
    const float* d_bt1 = (const float*)d_in[8];
    const float* d_W2  = (const float*)d_in[9];
    const float* d_b2  = (const float*)d_in[10];
    const float* d_g2  = (const float*)d_in[11];
    const float* d_bt2 = (const float*)d_in[12];
    float* out = (float*)d_out;

    char* ws = (char*)d_ws;
    size_t o = 0;
    auto take = [&](size_t bytes) -> char* {
        char* p = ws + o;
        o += (bytes + 255) & ~(size_t)255;
        return p;
    };
    int*            cnt     = (int*)take((N_NODES + 1) * sizeof(int));
    int*            row_ptr = (int*)take((N_NODES + 1) * sizeof(int));
    int*            row_run = (int*)take((N_NODES + 1) * sizeof(int));
    int*            part    = (int*)take(256 * sizeof(int));
    int*            pbase   = (int*)take(256 * sizeof(int));
    int2*           edata   = (int2*)take(N_EDGES * sizeof(int2));
    unsigned int*   hb0     = (unsigned int*)take((size_t)N_NODES * D * 2);   // bf16 input h
    unsigned int*   xh      = (unsigned int*)take((size_t)N_NODES * D * 2);
    unsigned int*   xl      = (unsigned int*)take((size_t)N_NODES * D * 2);
    float*          y       = (float*)take((size_t)N_NODES * D * sizeof(float));
    unsigned short* t2b     = (unsigned short*)take((size_t)N_NODES * D * 2);  // bf16 t2
    unsigned short* W1th    = (unsigned short*)take((size_t)NLAYERS * D * D * 2);
    unsigned short* W1tl    = (unsigned short*)take((size_t)NLAYERS * D * D * 2);
    unsigned short* W2th    = (unsigned short*)take((size_t)NLAYERS * D * D * 2);
    unsigned short* W2tl    = (unsigned short*)take((size_t)NLAYERS * D * D * 2);
    float*          stats1  = (float*)take(2 * D * sizeof(float));
    float*          stats2  = (float*)take(2 * D * sizeof(float));
    (void)ws_size; (void)in_sizes; (void)n_in; (void)out_size;

    // CSR build (dst/src/ew invariant across layers). k_wconv also zeros cnt.
    k_wconv<<<NLAYERS * D * D / 256, 256, 0, stream>>>(d_W1, d_W2, W1th, W1tl, W2th, W2tl, cnt);
    k_hist<<<N_EDGES / 256, 256, 0, stream>>>(d_dst, cnt);
    k_part<<<NB_SCAN, 256, 0, stream>>>(cnt, part);
    k_scanpart<<<1, 256, 0, stream>>>(part, pbase);
    k_emit<<<NB_SCAN, 256, 0, stream>>>(cnt, pbase, row_ptr, row_run);
    k_scatter<<<N_EDGES / 256, 256, 0, stream>>>(d_src, d_dst, d_ew, row_run, edata);
    k_h2b<<<N_NODES * D / 2 / 256, 256, 0, stream>>>(d_h, hb0);

    for (int l = 0; l < NLAYERS; ++l) {
        if (l == 0) {
            k_agg<0><<<N_NODES / 4, 256, 0, stream>>>(hb0, nullptr, nullptr, nullptr,
                                                      row_ptr, edata, d_eps, l, xh, xl, stats1);
        } else {
            k_agg<1><<<N_NODES / 4, 256, 0, stream>>>((const unsigned int*)t2b, stats2,
                                                      d_g2 + (l - 1) * D, d_bt2 + (l - 1) * D,
                                                      row_ptr, edata, d_eps, l, xh, xl, stats1);
        }
        k_gemm1<<<N_NODES / 64, 256, 0, stream>>>(xh, xl, W1th + l * D * D, W1tl + l * D * D,
                                                  d_b1 + l * D, y, stats1, stats2);
        k_gemm2<<<N_NODES / 64, 256, 0, stream>>>(y, stats1, d_g1 + l * D, d_bt1 + l * D,
                                                  W2th + l * D * D, W2tl + l * D * D,
                                                  d_b2 + l * D, t2b, stats2);
    }
    k_bnout<<<N_NODES * D / 2 / 256, 256, 0, stream>>>((const unsigned int*)t2b, stats2,
                                                       d_g2 + 2 * D, d_bt2 + 2 * D, out);
}